// Round 6
// baseline (165.235 us; speedup 1.0000x reference)
//
#include <hip/hip_runtime.h>
#include <cstddef>
#include <cstdint>

typedef float  f32x4  __attribute__((ext_vector_type(4)));
typedef __bf16 bf16x8 __attribute__((ext_vector_type(8)));
typedef unsigned short ushort_t;
typedef unsigned int __attribute__((address_space(1))) u32_g;
typedef unsigned int __attribute__((address_space(3))) u32_l;

#define S_LEN  2048
#define DMODEL 1024
#define NH     16
#define QKV_LD 3072   // fused QKV row stride (Q|K|V)

static __device__ __forceinline__ ushort_t f2bf(float f) {
    union { float f; unsigned u; } v; v.f = f;
    unsigned r = (v.u + 0x7FFFu + ((v.u >> 16) & 1u)) >> 16;
    return (ushort_t)r;
}
static __device__ __forceinline__ float bf2f(ushort_t b) {
    union { unsigned u; float f; } v; v.u = ((unsigned)b) << 16;
    return v.f;
}
// fast round-to-nearest (no tie-even) — valid for positive finite p
static __device__ __forceinline__ unsigned f2bf_rn_u(float f) {
    union { float f; unsigned u; } v; v.f = f;
    return (v.u + 0x8000u) >> 16;
}
// async 16B global->LDS; lds dst = wave-uniform base + lane*16
static __device__ __forceinline__ void load_lds16(const void* g, void* l) {
    __builtin_amdgcn_global_load_lds((const u32_g*)g, (u32_l*)l, 16, 0, 0);
}
static __device__ __forceinline__ int rel_bucket(int rp) {
    int arp = rp < 0 ? -rp : rp;
    int bucket;
    if (arp < 8) bucket = arp;
    else { int lg = 33 - __clz(arp * arp); bucket = lg < 15 ? lg : 15; }
    return rp > 0 ? bucket + 16 : bucket;
}

// ---------------- cast X (fp32 -> bf16), elementwise ----------------
__global__ __launch_bounds__(256) void cast_x(const float* __restrict__ X,
                                              ushort_t* __restrict__ Xb, int n4) {
    int i = blockIdx.x * 256 + threadIdx.x;
    if (i < n4) {
        float4 v = ((const float4*)X)[i];
        ushort4 o = make_ushort4(f2bf(v.x), f2bf(v.y), f2bf(v.z), f2bf(v.w));
        ((ushort4*)Xb)[i] = o;
    }
}

// ------------- weight transpose+cast: W[k][n] fp32 -> W^T[n][k] bf16 -------------
__global__ __launch_bounds__(256) void wcast(
    const float* __restrict__ Wq, const float* __restrict__ Wk,
    const float* __restrict__ Wv, const float* __restrict__ Wo,
    ushort_t* __restrict__ Wt, ushort_t* __restrict__ Wot)
{
    __shared__ float T[64][68];
    const int z = blockIdx.z;
    const float* W = (z == 0) ? Wq : (z == 1) ? Wk : (z == 2) ? Wv : Wo;
    ushort_t* Out = (z == 3) ? Wot : (Wt + (size_t)z * 1024 * 1024);
    const int k0 = blockIdx.y * 64, n0 = blockIdx.x * 64;
    const int t = threadIdx.x;
    #pragma unroll
    for (int i = 0; i < 4; i++) {
        int g = i * 256 + t; int kl = g >> 4, ng = g & 15;
        float4 v = *(const float4*)&W[(size_t)(k0 + kl) * 1024 + n0 + ng * 4];
        *(float4*)&T[kl][ng * 4] = v;
    }
    __syncthreads();
    #pragma unroll
    for (int i = 0; i < 2; i++) {
        int g = i * 256 + t; int nl = g >> 3, kg = g & 7;
        alignas(16) ushort_t pk[8];
        #pragma unroll
        for (int j = 0; j < 8; j++) pk[j] = f2bf(T[kg * 8 + j][nl]);
        *(uint4*)&Out[(size_t)(n0 + nl) * 1024 + k0 + kg * 8] = *(uint4*)pk;
    }
}

// ------------- per-head V transpose: QKV V-section -> Vt[h][d][s] bf16 -------------
__global__ __launch_bounds__(256) void vt_trans(const ushort_t* __restrict__ QKV,
                                                ushort_t* __restrict__ Vt) {
    __shared__ ushort_t T[64][80];
    const int h = blockIdx.y, s0 = blockIdx.x * 64;
    const int t = threadIdx.x;
    #pragma unroll
    for (int i = 0; i < 2; i++) {
        int g = i * 256 + t; int sl = g >> 3, dg = g & 7;
        *(uint4*)&T[sl][dg * 8] =
            *(const uint4*)&QKV[(size_t)(s0 + sl) * QKV_LD + 2048 + h * 64 + dg * 8];
    }
    __syncthreads();
    #pragma unroll
    for (int i = 0; i < 2; i++) {
        int g = i * 256 + t; int dl = g >> 3, sg = g & 7;
        alignas(16) ushort_t pk[8];
        #pragma unroll
        for (int j = 0; j < 8; j++) pk[j] = T[sg * 8 + j][dl];
        *(uint4*)&Vt[(size_t)(h * 64 + dl) * S_LEN + s0 + sg * 8] = *(uint4*)pk;
    }
}

// ---------------- bf16 MFMA GEMM 128x128 (QKV projection) ----------------
__global__ __launch_bounds__(256) void gemm_bf16(
    const ushort_t* __restrict__ A, const ushort_t* __restrict__ B,
    ushort_t* __restrict__ Cout, int M, int N, int K)
{
    __shared__ ushort_t As[128 * 64];
    __shared__ ushort_t Bs[128 * 64];
    const int tid = threadIdx.x;
    const int w = tid >> 6, lane = tid & 63, quad = lane >> 4, cid = lane & 15;
    const int wm = w >> 1, wn = w & 1;
    const int m0 = blockIdx.y * 128, n0 = blockIdx.x * 128;

    f32x4 acc[4][4] = {};

    for (int k0 = 0; k0 < K; k0 += 64) {
        #pragma unroll
        for (int i = 0; i < 4; i++) {
            int g = i * 256 + tid; int r = g >> 3, kg = g & 7;
            int dg = kg ^ (r & 7);
            load_lds16(A + (size_t)(m0 + r) * K + k0 + dg * 8, &As[(i * 256 + w * 64) * 8]);
            load_lds16(B + (size_t)(n0 + r) * K + k0 + dg * 8, &Bs[(i * 256 + w * 64) * 8]);
        }
        __syncthreads();
        #pragma unroll
        for (int kk = 0; kk < 2; kk++) {
            bf16x8 af[4], bf[4];
            #pragma unroll
            for (int t = 0; t < 4; t++) {
                int m = wm * 64 + t * 16 + cid;
                af[t] = *(const bf16x8*)&As[m * 64 + (((kk * 4 + quad) ^ (m & 7)) * 8)];
                int n = wn * 64 + t * 16 + cid;
                bf[t] = *(const bf16x8*)&Bs[n * 64 + (((kk * 4 + quad) ^ (n & 7)) * 8)];
            }
            #pragma unroll
            for (int i = 0; i < 4; i++)
                #pragma unroll
                for (int j = 0; j < 4; j++)
                    acc[i][j] = __builtin_amdgcn_mfma_f32_16x16x32_bf16(af[i], bf[j], acc[i][j], 0, 0, 0);
        }
        __syncthreads();
    }
    #pragma unroll
    for (int i = 0; i < 4; i++)
        #pragma unroll
        for (int j = 0; j < 4; j++)
            #pragma unroll
            for (int r = 0; r < 4; r++) {
                int row = m0 + wm * 64 + i * 16 + quad * 4 + r;
                int col = n0 + wn * 64 + j * 16 + cid;
                Cout[(size_t)row * N + col] = f2bf(acc[i][j][r]);
            }
}

// ---------------- bf16 MFMA GEMM 64x64, fp32 out (output projection) ----------------
__global__ __launch_bounds__(256) void gemm64_f32(
    const ushort_t* __restrict__ A, const ushort_t* __restrict__ B,
    float* __restrict__ Cout, int M, int N, int K)
{
    __shared__ ushort_t As[64 * 64];
    __shared__ ushort_t Bs[64 * 64];
    const int tid = threadIdx.x;
    const int w = tid >> 6, lane = tid & 63, quad = lane >> 4, cid = lane & 15;
    const int wm = w >> 1, wn = w & 1;
    const int m0 = blockIdx.y * 64, n0 = blockIdx.x * 64;

    f32x4 acc[2][2] = {};

    for (int k0 = 0; k0 < K; k0 += 64) {
        #pragma unroll
        for (int i = 0; i < 2; i++) {
            int g = i * 256 + tid; int r = g >> 3, kg = g & 7;
            int dg = kg ^ (r & 7);
            load_lds16(A + (size_t)(m0 + r) * K + k0 + dg * 8, &As[(i * 256 + w * 64) * 8]);
            load_lds16(B + (size_t)(n0 + r) * K + k0 + dg * 8, &Bs[(i * 256 + w * 64) * 8]);
        }
        __syncthreads();
        #pragma unroll
        for (int kk = 0; kk < 2; kk++) {
            bf16x8 af[2], bf[2];
            #pragma unroll
            for (int t = 0; t < 2; t++) {
                int m = wm * 32 + t * 16 + cid;
                af[t] = *(const bf16x8*)&As[m * 64 + (((kk * 4 + quad) ^ (m & 7)) * 8)];
                int n = wn * 32 + t * 16 + cid;
                bf[t] = *(const bf16x8*)&Bs[n * 64 + (((kk * 4 + quad) ^ (n & 7)) * 8)];
            }
            #pragma unroll
            for (int i = 0; i < 2; i++)
                #pragma unroll
                for (int j = 0; j < 2; j++)
                    acc[i][j] = __builtin_amdgcn_mfma_f32_16x16x32_bf16(af[i], bf[j], acc[i][j], 0, 0, 0);
        }
        __syncthreads();
    }
    #pragma unroll
    for (int i = 0; i < 2; i++)
        #pragma unroll
        for (int j = 0; j < 2; j++)
            #pragma unroll
            for (int r = 0; r < 4; r++) {
                int row = m0 + wm * 32 + i * 16 + quad * 4 + r;
                int col = n0 + wn * 32 + j * 16 + cid;
                Cout[(size_t)row * N + col] = acc[i][j][r];
            }
}

// ---------------- MFMA flash attention v3b: S^T/O^T, barrier-fenced P ----------------
// Grid (32, 16, 2): q-tile(64), head, K-segment of 1024. Block: 128 threads = 2
// waves, each wave owns 32 q rows (2 groups of 16). S^T = K.Q^T puts a FIXED q
// per lane (q = cid) with 4-consecutive-key runs -> vector bias reads, b64 P
// writes, pure-VALU row sums. O^T = V^T.P^T reads P as B-operand (b128).
// P round-trip is barrier-fenced (R5's unfenced version raced under replay).
__global__ __launch_bounds__(128) void attn_mfma(
    const ushort_t* __restrict__ QKV, const ushort_t* __restrict__ Vt,
    const float* __restrict__ rel_bias,
    ushort_t* __restrict__ Opart, float* __restrict__ Lpart)
{
    __shared__ float    biasH[32];
    __shared__ float    tab[1088];       // bias[idx], rp = idx-63+s0-q0 (4.25 KB)
    __shared__ ushort_t Ks[64 * 64];     // [key][dgran ^ key&7]     8 KB
    __shared__ ushort_t Vs[64 * 64];     // [d][keygran ^ d&7]       8 KB
    __shared__ ushort_t Ps[2][32 * 64];  // per-wave [q][kgran ^ q&7] 8 KB

    const int tid = threadIdx.x;
    const int w = tid >> 6, lane = tid & 63, quad = lane >> 4, cid = lane & 15;
    const int h = blockIdx.y, q0 = blockIdx.x * 64;
    const int seg = blockIdx.z, s0 = seg * 1024;

    if (tid < 32) biasH[tid] = rel_bias[tid * NH + h];
    __syncthreads();
    for (int idx = tid; idx < 1087; idx += 128)
        tab[idx] = biasH[rel_bucket(idx - 63 + s0 - q0)];

    // Q^T B-operand frags: lane supplies B[k=quad*8+j][n=cid] = Q[qb+cid][kk*32+quad*8+j]
    bf16x8 qf[2][2];   // [group][kk]
    #pragma unroll
    for (int g = 0; g < 2; g++) {
        int q = q0 + w * 32 + g * 16 + cid;
        #pragma unroll
        for (int kk = 0; kk < 2; kk++)
            qf[g][kk] = *(const bf16x8*)&QKV[(size_t)q * QKV_LD + h * 64 + kk * 32 + quad * 8];
    }

    f32x4 Oacc[2][4] = {};      // [group][dt]: O^T rows d=dt*16+quad*4+r, col q=g*16+cid
    float lsum[2] = {0.f, 0.f};

    ushort_t* Pw = &Ps[w][0];
    const int c7 = cid & 7;

    for (int k0 = s0; k0 < s0 + 1024; k0 += 64) {
        __syncthreads();   // prior chunk's Ks/Vs/Ps reads done (1st iter: tab init)
        #pragma unroll
        for (int i = 0; i < 4; i++) {
            int g = i * 128 + tid; int row = g >> 3, kg = g & 7;
            int dg = kg ^ (row & 7);
            load_lds16(QKV + (size_t)(k0 + row) * QKV_LD + 1024 + h * 64 + dg * 8,
                       &Ks[(i * 128 + w * 64) * 8]);
            load_lds16(Vt + (size_t)(h * 64 + row) * S_LEN + k0 + dg * 8,
                       &Vs[(i * 128 + w * 64) * 8]);
        }
        __syncthreads();

        // S^T = K . Q^T : per tile tj, lane gets keys tj*16+quad*4+r at q=g*16+cid
        f32x4 S[2][4] = {};
        #pragma unroll
        for (int kk = 0; kk < 2; kk++) {
            bf16x8 kf[4];
            #pragma unroll
            for (int tj = 0; tj < 4; tj++) {
                int key = tj * 16 + cid;
                kf[tj] = *(const bf16x8*)&Ks[key * 64 + (((kk * 4 + quad) ^ (key & 7)) * 8)];
            }
            #pragma unroll
            for (int tj = 0; tj < 4; tj++) {
                S[0][tj] = __builtin_amdgcn_mfma_f32_16x16x32_bf16(kf[tj], qf[0][kk], S[0][tj], 0, 0, 0);
                S[1][tj] = __builtin_amdgcn_mfma_f32_16x16x32_bf16(kf[tj], qf[1][kk], S[1][tj], 0, 0, 0);
            }
        }

        // bias + exp + row-sum + b64 P store (lane's 4 keys are consecutive)
        #pragma unroll
        for (int g = 0; g < 2; g++) {
            const int dq = w * 32 + g * 16 + cid;
            const int qrow = (g * 16 + cid) * 64;
            #pragma unroll
            for (int tj = 0; tj < 4; tj++) {
                int idxb = (k0 - s0) + tj * 16 + quad * 4 + 63 - dq;
                float p0 = __expf(S[g][tj][0] + tab[idxb]);
                float p1 = __expf(S[g][tj][1] + tab[idxb + 1]);
                float p2 = __expf(S[g][tj][2] + tab[idxb + 2]);
                float p3 = __expf(S[g][tj][3] + tab[idxb + 3]);
                lsum[g] += (p0 + p1) + (p2 + p3);
                uint2 pk;
                pk.x = f2bf_rn_u(p0) | (f2bf_rn_u(p1) << 16);
                pk.y = f2bf_rn_u(p2) | (f2bf_rn_u(p3) << 16);
                int gs = (tj * 2 + (quad >> 1)) ^ c7;   // granule holds keys gs*8..+7
                *(uint2*)&Pw[qrow + gs * 8 + (quad & 1) * 4] = pk;
            }
        }
        __syncthreads();   // fence P writes before cross-lane P reads (R5 fix)

        // O^T += V^T . P^T  (A = V^T rows d; B = P^T, lane k=quad*8+j keys, n=cid)
        #pragma unroll
        for (int kh = 0; kh < 2; kh++) {
            bf16x8 pB[2];
            #pragma unroll
            for (int g = 0; g < 2; g++)
                pB[g] = *(const bf16x8*)&Pw[(g * 16 + cid) * 64 + (((kh * 4 + quad) ^ c7) * 8)];
            #pragma unroll
            for (int dt = 0; dt < 4; dt++) {
                int d = dt * 16 + cid;
                bf16x8 vf = *(const bf16x8*)&Vs[d * 64 + (((kh * 4 + quad) ^ (d & 7)) * 8)];
                Oacc[0][dt] = __builtin_amdgcn_mfma_f32_16x16x32_bf16(vf, pB[0], Oacc[0][dt], 0, 0, 0);
                Oacc[1][dt] = __builtin_amdgcn_mfma_f32_16x16x32_bf16(vf, pB[1], Oacc[1][dt], 0, 0, 0);
            }
        }
    }

    // l: reduce across the 4 quads (lane's lsum covers its q, quarter of keys)
    #pragma unroll
    for (int g = 0; g < 2; g++) {
        float l = lsum[g];
        l += __shfl_xor(l, 16);
        l += __shfl_xor(l, 32);
        if (quad == 0)
            Lpart[((size_t)seg * NH + h) * S_LEN + q0 + w * 32 + g * 16 + cid] = l;
    }

    // partial O^T -> Opart[seg][q][h*64+d], pack 4 consecutive d per store
    #pragma unroll
    for (int g = 0; g < 2; g++) {
        int row = q0 + w * 32 + g * 16 + cid;
        #pragma unroll
        for (int dt = 0; dt < 4; dt++) {
            uint2 pk;
            pk.x = (unsigned)f2bf(Oacc[g][dt][0]) | ((unsigned)f2bf(Oacc[g][dt][1]) << 16);
            pk.y = (unsigned)f2bf(Oacc[g][dt][2]) | ((unsigned)f2bf(Oacc[g][dt][3]) << 16);
            *(uint2*)&Opart[(size_t)seg * (S_LEN * DMODEL) + (size_t)row * DMODEL
                            + h * 64 + dt * 16 + quad * 4] = pk;
        }
    }
}

// ---------------- combine split-K partials: Ctx = (O0+O1)/(l0+l1) ----------------
__global__ __launch_bounds__(256) void attn_reduce(
    const ushort_t* __restrict__ Opart, const float* __restrict__ Lpart,
    ushort_t* __restrict__ Ctx)
{
    int i = blockIdx.x * 256 + threadIdx.x;   // over 2048*1024/8 uint4-of-bf16
    int row = i >> 7;                          // 128 x 8 elems per row
    int h = (i & 127) >> 3;
    float l = Lpart[h * S_LEN + row] + Lpart[(NH + h) * S_LEN + row];
    float inv = 1.f / l;
    uint4 a = ((const uint4*)Opart)[i];
    uint4 b = ((const uint4*)Opart)[i + S_LEN * DMODEL / 8];
    alignas(16) ushort_t oa[8]; *(uint4*)oa = a;
    alignas(16) ushort_t ob[8]; *(uint4*)ob = b;
    alignas(16) ushort_t oc[8];
    #pragma unroll
    for (int j = 0; j < 8; j++) oc[j] = f2bf((bf2f(oa[j]) + bf2f(ob[j])) * inv);
    ((uint4*)Ctx)[i] = *(uint4*)oc;
}

// ---------------- launch ----------------
extern "C" void kernel_launch(void* const* d_in, const int* in_sizes, int n_in,
                              void* d_out, int out_size, void* d_ws, size_t ws_size,
                              hipStream_t stream) {
    const float* X  = (const float*)d_in[0];
    const float* Wq = (const float*)d_in[1];
    const float* Wk = (const float*)d_in[2];
    const float* Wv = (const float*)d_in[3];
    const float* Wo = (const float*)d_in[4];
    const float* rb = (const float*)d_in[5];
    float* out = (float*)d_out;

    ushort_t* ws = (ushort_t*)d_ws;
    const size_t M1 = 1024 * 1024;
    // Region timeline (ushort units, 14M = 28 MB):
    //  0..2M   Xb     -> dead after QKV gemm -> Opart (0..4M)
    //  2..5M   Wt     -> dead after QKV gemm -> Lpart (at 4M)
    //  5..6M   Wot    (live until final gemm)
    //  6..12M  QKV    -> dead after attn     -> Ctx (6..8M)
    // 12..14M  Vt     -> dead after attn
    ushort_t* Xb    = ws;
    ushort_t* Wt    = ws + 2 * M1;
    ushort_t* Wot   = ws + 5 * M1;
    ushort_t* QKV   = ws + 6 * M1;
    ushort_t* Vt    = ws + 12 * M1;
    ushort_t* Opart = ws;
    float*    Lpart = (float*)(ws + 4 * M1);
    ushort_t* Ctx   = ws + 6 * M1;

    cast_x<<<dim3((S_LEN * DMODEL / 4 + 255) / 256), 256, 0, stream>>>(X, Xb, S_LEN * DMODEL / 4);
    wcast<<<dim3(16, 16, 4), 256, 0, stream>>>(Wq, Wk, Wv, Wo, Wt, Wot);
    gemm_bf16<<<dim3(24, 16), 256, 0, stream>>>(Xb, Wt, QKV, S_LEN, 3072, DMODEL);
    vt_trans<<<dim3(32, 16), 256, 0, stream>>>(QKV, Vt);
    attn_mfma<<<dim3(32, 16, 2), 128, 0, stream>>>(QKV, Vt, rb, Opart, Lpart);
    attn_reduce<<<dim3(S_LEN * DMODEL / 8 / 256), 256, 0, stream>>>(Opart, Lpart, Ctx);
    gemm64_f32<<<dim3(16, 32), 256, 0, stream>>>(Ctx, Wot, out, S_LEN, DMODEL, DMODEL);
}

// Round 8
// 161.526 us; speedup vs baseline: 1.0230x; 1.0230x over previous
//
#include <hip/hip_runtime.h>
#include <cstddef>
#include <cstdint>

typedef float  f32x4  __attribute__((ext_vector_type(4)));
typedef __bf16 bf16x8 __attribute__((ext_vector_type(8)));
typedef unsigned short ushort_t;
typedef unsigned int __attribute__((address_space(1))) u32_g;
typedef unsigned int __attribute__((address_space(3))) u32_l;

#define S_LEN  2048
#define DMODEL 1024
#define NH     16
#define QKV_LD 3072   // fused QKV row stride (Q|K|V)

static __device__ __forceinline__ ushort_t f2bf(float f) {
    union { float f; unsigned u; } v; v.f = f;
    unsigned r = (v.u + 0x7FFFu + ((v.u >> 16) & 1u)) >> 16;
    return (ushort_t)r;
}
static __device__ __forceinline__ float bf2f(ushort_t b) {
    union { unsigned u; float f; } v; v.u = ((unsigned)b) << 16;
    return v.f;
}
// fast round-to-nearest (no tie-even) — valid for positive finite p
static __device__ __forceinline__ unsigned f2bf_rn_u(float f) {
    union { float f; unsigned u; } v; v.f = f;
    return (v.u + 0x8000u) >> 16;
}
// async 16B global->LDS; lds dst = wave-uniform base + lane*16
static __device__ __forceinline__ void load_lds16(const void* g, void* l) {
    __builtin_amdgcn_global_load_lds((const u32_g*)g, (u32_l*)l, 16, 0, 0);
}
static __device__ __forceinline__ int rel_bucket(int rp) {
    int arp = rp < 0 ? -rp : rp;
    int bucket;
    if (arp < 8) bucket = arp;
    else { int lg = 33 - __clz(arp * arp); bucket = lg < 15 ? lg : 15; }
    return rp > 0 ? bucket + 16 : bucket;
}

// ---------------- prep: fused weight transpose+cast AND X cast ----------------
// blocks [0,1024): wcast (z=b>>8, y=(b>>4)&15, x=b&15); blocks [1024,3072): X cast.
__global__ __launch_bounds__(256) void prep(
    const float* __restrict__ X,
    const float* __restrict__ Wq, const float* __restrict__ Wk,
    const float* __restrict__ Wv, const float* __restrict__ Wo,
    ushort_t* __restrict__ Xb, ushort_t* __restrict__ Wt, ushort_t* __restrict__ Wot)
{
    const int b = blockIdx.x;
    const int t = threadIdx.x;
    if (b < 1024) {
        __shared__ float T[64][68];
        const int z = b >> 8;
        const float* W = (z == 0) ? Wq : (z == 1) ? Wk : (z == 2) ? Wv : Wo;
        ushort_t* Out = (z == 3) ? Wot : (Wt + (size_t)z * 1024 * 1024);
        const int k0 = ((b >> 4) & 15) * 64, n0 = (b & 15) * 64;
        #pragma unroll
        for (int i = 0; i < 4; i++) {
            int g = i * 256 + t; int kl = g >> 4, ng = g & 15;
            float4 v = *(const float4*)&W[(size_t)(k0 + kl) * 1024 + n0 + ng * 4];
            *(float4*)&T[kl][ng * 4] = v;
        }
        __syncthreads();
        #pragma unroll
        for (int i = 0; i < 2; i++) {
            int g = i * 256 + t; int nl = g >> 3, kg = g & 7;
            alignas(16) ushort_t pk[8];
            #pragma unroll
            for (int j = 0; j < 8; j++) pk[j] = f2bf(T[kg * 8 + j][nl]);
            *(uint4*)&Out[(size_t)(n0 + nl) * 1024 + k0 + kg * 8] = *(uint4*)pk;
        }
    } else {
        int i = (b - 1024) * 256 + t;   // < 524288 float4s
        float4 v = ((const float4*)X)[i];
        ushort4 o = make_ushort4(f2bf(v.x), f2bf(v.y), f2bf(v.z), f2bf(v.w));
        ((ushort4*)Xb)[i] = o;
    }
}

// ------------- per-head V transpose: QKV V-section -> Vt[h][d][s] bf16 -------------
__global__ __launch_bounds__(256) void vt_trans(const ushort_t* __restrict__ QKV,
                                                ushort_t* __restrict__ Vt) {
    __shared__ ushort_t T[64][80];
    const int h = blockIdx.y, s0 = blockIdx.x * 64;
    const int t = threadIdx.x;
    #pragma unroll
    for (int i = 0; i < 2; i++) {
        int g = i * 256 + t; int sl = g >> 3, dg = g & 7;
        *(uint4*)&T[sl][dg * 8] =
            *(const uint4*)&QKV[(size_t)(s0 + sl) * QKV_LD + 2048 + h * 64 + dg * 8];
    }
    __syncthreads();
    #pragma unroll
    for (int i = 0; i < 2; i++) {
        int g = i * 256 + t; int dl = g >> 3, sg = g & 7;
        alignas(16) ushort_t pk[8];
        #pragma unroll
        for (int j = 0; j < 8; j++) pk[j] = T[sg * 8 + j][dl];
        *(uint4*)&Vt[(size_t)(h * 64 + dl) * S_LEN + s0 + sg * 8] = *(uint4*)pk;
    }
}

// ---------------- bf16 MFMA GEMM 128x128 (QKV projection) — R6-proven ----------------
__global__ __launch_bounds__(256) void gemm_bf16(
    const ushort_t* __restrict__ A, const ushort_t* __restrict__ B,
    ushort_t* __restrict__ Cout, int M, int N, int K)
{
    __shared__ ushort_t As[128 * 64];
    __shared__ ushort_t Bs[128 * 64];
    const int tid = threadIdx.x;
    const int w = tid >> 6, lane = tid & 63, quad = lane >> 4, cid = lane & 15;
    const int wm = w >> 1, wn = w & 1;
    const int m0 = blockIdx.y * 128, n0 = blockIdx.x * 128;

    f32x4 acc[4][4] = {};

    for (int k0 = 0; k0 < K; k0 += 64) {
        #pragma unroll
        for (int i = 0; i < 4; i++) {
            int g = i * 256 + tid; int r = g >> 3, kg = g & 7;
            int dg = kg ^ (r & 7);
            load_lds16(A + (size_t)(m0 + r) * K + k0 + dg * 8, &As[(i * 256 + w * 64) * 8]);
            load_lds16(B + (size_t)(n0 + r) * K + k0 + dg * 8, &Bs[(i * 256 + w * 64) * 8]);
        }
        __syncthreads();
        #pragma unroll
        for (int kk = 0; kk < 2; kk++) {
            bf16x8 af[4], bf[4];
            #pragma unroll
            for (int t = 0; t < 4; t++) {
                int m = wm * 64 + t * 16 + cid;
                af[t] = *(const bf16x8*)&As[m * 64 + (((kk * 4 + quad) ^ (m & 7)) * 8)];
                int n = wn * 64 + t * 16 + cid;
                bf[t] = *(const bf16x8*)&Bs[n * 64 + (((kk * 4 + quad) ^ (n & 7)) * 8)];
            }
            #pragma unroll
            for (int i = 0; i < 4; i++)
                #pragma unroll
                for (int j = 0; j < 4; j++)
                    acc[i][j] = __builtin_amdgcn_mfma_f32_16x16x32_bf16(af[i], bf[j], acc[i][j], 0, 0, 0);
        }
        __syncthreads();
    }
    #pragma unroll
    for (int i = 0; i < 4; i++)
        #pragma unroll
        for (int j = 0; j < 4; j++)
            #pragma unroll
            for (int r = 0; r < 4; r++) {
                int row = m0 + wm * 64 + i * 16 + quad * 4 + r;
                int col = n0 + wn * 64 + j * 16 + cid;
                Cout[(size_t)row * N + col] = f2bf(acc[i][j][r]);
            }
}

// ---------------- MFMA flash attention v5: S^T/O^T + dbuf, barrier-fenced P ----------------
// Grid (16, 16, 2): 128-q tile, head, K-segment of 1024. 256 threads = 4 waves,
// each wave owns 32 q (2 groups of 16). Double-buffered Ks/Vs; DMA for chunk
// it+1 issued right after the top barrier -> overlaps QK^T+softmax of chunk it.
// P round-trip uses the R4/R6-proven __syncthreads fence (2 barriers/chunk).
__global__ __launch_bounds__(256) void attn_mfma(
    const ushort_t* __restrict__ QKV, const ushort_t* __restrict__ Vt,
    const float* __restrict__ rel_bias,
    ushort_t* __restrict__ Opart, float* __restrict__ Lpart)
{
    __shared__ float    biasH[32];
    __shared__ float    tab[1152];          // rp = idx-127+s0-q0 (4.5 KB)
    __shared__ ushort_t Ks[2][64 * 64];     // 16 KB
    __shared__ ushort_t Vs[2][64 * 64];     // 16 KB
    __shared__ ushort_t Ps[4][32 * 64];     // per-wave, 16 KB

    const int tid = threadIdx.x;
    const int w = tid >> 6, lane = tid & 63, quad = lane >> 4, cid = lane & 15;
    const int h = blockIdx.y, q0 = blockIdx.x * 128;
    const int seg = blockIdx.z, s0 = seg * 1024;
    const int c7 = cid & 7;

    if (tid < 32) biasH[tid] = rel_bias[tid * NH + h];
    __syncthreads();
    for (int idx = tid; idx < 1151; idx += 256)
        tab[idx] = biasH[rel_bucket(idx - 127 + s0 - q0)];

    // Q^T B-operand frags: B[k=quad*8+j][n=cid] = Q[q][kk*32+quad*8+j]
    bf16x8 qf[2][2];
    #pragma unroll
    for (int g = 0; g < 2; g++) {
        int q = q0 + w * 32 + g * 16 + cid;
        #pragma unroll
        for (int kk = 0; kk < 2; kk++)
            qf[g][kk] = *(const bf16x8*)&QKV[(size_t)q * QKV_LD + h * 64 + kk * 32 + quad * 8];
    }

    auto stage = [&](int k0, int b) {
        #pragma unroll
        for (int i = 0; i < 2; i++) {
            int g = i * 256 + tid; int row = g >> 3, kg = g & 7;
            int dg = kg ^ (row & 7);
            load_lds16(QKV + (size_t)(k0 + row) * QKV_LD + 1024 + h * 64 + dg * 8,
                       &Ks[b][(i * 256 + w * 64) * 8]);
            load_lds16(Vt + (size_t)(h * 64 + row) * S_LEN + k0 + dg * 8,
                       &Vs[b][(i * 256 + w * 64) * 8]);
        }
    };
    stage(s0, 0);

    f32x4 Oacc[2][4] = {};      // [group][dt]: O^T rows d=dt*16+quad*4+r, col q
    float lsum[2] = {0.f, 0.f};
    ushort_t* Pw = &Ps[w][0];

    for (int it = 0; it < 16; ++it) {
        __syncthreads();   // chunk `it` landed; prior chunk's Ks/Vs/Ps reads done
        if (it + 1 < 16) stage(s0 + (it + 1) * 64, (it + 1) & 1);   // overlap
        const ushort_t* Kb = Ks[it & 1];
        const ushort_t* Vb = Vs[it & 1];
        const int k0s = it * 64;

        // S^T = K . Q^T : lane gets keys tj*16+quad*4+r at fixed q
        f32x4 S[2][4] = {};
        #pragma unroll
        for (int kk = 0; kk < 2; kk++) {
            bf16x8 kf[4];
            #pragma unroll
            for (int tj = 0; tj < 4; tj++) {
                int key = tj * 16 + cid;
                kf[tj] = *(const bf16x8*)&Kb[key * 64 + (((kk * 4 + quad) ^ (key & 7)) * 8)];
            }
            #pragma unroll
            for (int tj = 0; tj < 4; tj++) {
                S[0][tj] = __builtin_amdgcn_mfma_f32_16x16x32_bf16(kf[tj], qf[0][kk], S[0][tj], 0, 0, 0);
                S[1][tj] = __builtin_amdgcn_mfma_f32_16x16x32_bf16(kf[tj], qf[1][kk], S[1][tj], 0, 0, 0);
            }
        }

        // bias + exp + row-sum + b64 P store
        #pragma unroll
        for (int g = 0; g < 2; g++) {
            const int dq = w * 32 + g * 16 + cid;
            const int qrow = (g * 16 + cid) * 64;
            #pragma unroll
            for (int tj = 0; tj < 4; tj++) {
                int idxb = k0s + tj * 16 + quad * 4 + 127 - dq;
                float p0 = __expf(S[g][tj][0] + tab[idxb]);
                float p1 = __expf(S[g][tj][1] + tab[idxb + 1]);
                float p2 = __expf(S[g][tj][2] + tab[idxb + 2]);
                float p3 = __expf(S[g][tj][3] + tab[idxb + 3]);
                lsum[g] += (p0 + p1) + (p2 + p3);
                uint2 pk;
                pk.x = f2bf_rn_u(p0) | (f2bf_rn_u(p1) << 16);
                pk.y = f2bf_rn_u(p2) | (f2bf_rn_u(p3) << 16);
                int gs = (tj * 2 + (quad >> 1)) ^ c7;
                *(uint2*)&Pw[qrow + gs * 8 + (quad & 1) * 4] = pk;
            }
        }
        __syncthreads();   // proven P fence (also drains in-flight prefetch early)

        // O^T += V^T . P^T
        #pragma unroll
        for (int kh = 0; kh < 2; kh++) {
            bf16x8 pB[2];
            #pragma unroll
            for (int g = 0; g < 2; g++)
                pB[g] = *(const bf16x8*)&Pw[(g * 16 + cid) * 64 + (((kh * 4 + quad) ^ c7) * 8)];
            #pragma unroll
            for (int dt = 0; dt < 4; dt++) {
                int d = dt * 16 + cid;
                bf16x8 vf = *(const bf16x8*)&Vb[d * 64 + (((kh * 4 + quad) ^ (d & 7)) * 8)];
                Oacc[0][dt] = __builtin_amdgcn_mfma_f32_16x16x32_bf16(vf, pB[0], Oacc[0][dt], 0, 0, 0);
                Oacc[1][dt] = __builtin_amdgcn_mfma_f32_16x16x32_bf16(vf, pB[1], Oacc[1][dt], 0, 0, 0);
            }
        }
    }

    // l: reduce across the 4 quads
    #pragma unroll
    for (int g = 0; g < 2; g++) {
        float l = lsum[g];
        l += __shfl_xor(l, 16);
        l += __shfl_xor(l, 32);
        if (quad == 0)
            Lpart[((size_t)seg * NH + h) * S_LEN + q0 + w * 32 + g * 16 + cid] = l;
    }

    // partial O^T -> Opart[seg][q][h*64+d]
    #pragma unroll
    for (int g = 0; g < 2; g++) {
        int row = q0 + w * 32 + g * 16 + cid;
        #pragma unroll
        for (int dt = 0; dt < 4; dt++) {
            uint2 pk;
            pk.x = (unsigned)f2bf(Oacc[g][dt][0]) | ((unsigned)f2bf(Oacc[g][dt][1]) << 16);
            pk.y = (unsigned)f2bf(Oacc[g][dt][2]) | ((unsigned)f2bf(Oacc[g][dt][3]) << 16);
            *(uint2*)&Opart[(size_t)seg * (S_LEN * DMODEL) + (size_t)row * DMODEL
                            + h * 64 + dt * 16 + quad * 4] = pk;
        }
    }
}

// ---------------- combine split-K partials: Ctx = (O0+O1)/(l0+l1) ----------------
__global__ __launch_bounds__(256) void attn_reduce(
    const ushort_t* __restrict__ Opart, const float* __restrict__ Lpart,
    ushort_t* __restrict__ Ctx)
{
    int i = blockIdx.x * 256 + threadIdx.x;   // over 2048*1024/8 uint4-of-bf16
    int row = i >> 7;                          // 128 x 8 elems per row
    int h = (i & 127) >> 3;
    float l = Lpart[h * S_LEN + row] + Lpart[(NH + h) * S_LEN + row];
    float inv = 1.f / l;
    uint4 a = ((const uint4*)Opart)[i];
    uint4 b = ((const uint4*)Opart)[i + S_LEN * DMODEL / 8];
    alignas(16) ushort_t oa[8]; *(uint4*)oa = a;
    alignas(16) ushort_t ob[8]; *(uint4*)ob = b;
    alignas(16) ushort_t oc[8];
    #pragma unroll
    for (int j = 0; j < 8; j++) oc[j] = f2bf((bf2f(oa[j]) + bf2f(ob[j])) * inv);
    ((uint4*)Ctx)[i] = *(uint4*)oc;
}

// ---------------- bf16 MFMA GEMM 64x64, fp32 out (output projection) — R6-proven ----------------
__global__ __launch_bounds__(256) void gemm64_f32(
    const ushort_t* __restrict__ A, const ushort_t* __restrict__ B,
    float* __restrict__ Cout, int M, int N, int K)
{
    __shared__ ushort_t As[64 * 64];
    __shared__ ushort_t Bs[64 * 64];
    const int tid = threadIdx.x;
    const int w = tid >> 6, lane = tid & 63, quad = lane >> 4, cid = lane & 15;
    const int wm = w >> 1, wn = w & 1;
    const int m0 = blockIdx.y * 64, n0 = blockIdx.x * 64;

    f32x4 acc[2][2] = {};

    for (int k0 = 0; k0 < K; k0 += 64) {
        #pragma unroll
        for (int i = 0; i < 2; i++) {
            int g = i * 256 + tid; int r = g >> 3, kg = g & 7;
            int dg = kg ^ (r & 7);
            load_lds16(A + (size_t)(m0 + r) * K + k0 + dg * 8, &As[(i * 256 + w * 64) * 8]);
            load_lds16(B + (size_t)(n0 + r) * K + k0 + dg * 8, &Bs[(i * 256 + w * 64) * 8]);
        }
        __syncthreads();
        #pragma unroll
        for (int kk = 0; kk < 2; kk++) {
            bf16x8 af[2], bf[2];
            #pragma unroll
            for (int t = 0; t < 2; t++) {
                int m = wm * 32 + t * 16 + cid;
                af[t] = *(const bf16x8*)&As[m * 64 + (((kk * 4 + quad) ^ (m & 7)) * 8)];
                int n = wn * 32 + t * 16 + cid;
                bf[t] = *(const bf16x8*)&Bs[n * 64 + (((kk * 4 + quad) ^ (n & 7)) * 8)];
            }
            #pragma unroll
            for (int i = 0; i < 2; i++)
                #pragma unroll
                for (int j = 0; j < 2; j++)
                    acc[i][j] = __builtin_amdgcn_mfma_f32_16x16x32_bf16(af[i], bf[j], acc[i][j], 0, 0, 0);
        }
        __syncthreads();
    }
    #pragma unroll
    for (int i = 0; i < 2; i++)
        #pragma unroll
        for (int j = 0; j < 2; j++)
            #pragma unroll
            for (int r = 0; r < 4; r++) {
                int row = m0 + wm * 32 + i * 16 + quad * 4 + r;
                int col = n0 + wn * 32 + j * 16 + cid;
                Cout[(size_t)row * N + col] = acc[i][j][r];
            }
}

// ---------------- launch ----------------
extern "C" void kernel_launch(void* const* d_in, const int* in_sizes, int n_in,
                              void* d_out, int out_size, void* d_ws, size_t ws_size,
                              hipStream_t stream) {
    const float* X  = (const float*)d_in[0];
    const float* Wq = (const float*)d_in[1];
    const float* Wk = (const float*)d_in[2];
    const float* Wv = (const float*)d_in[3];
    const float* Wo = (const float*)d_in[4];
    const float* rb = (const float*)d_in[5];
    float* out = (float*)d_out;

    ushort_t* ws = (ushort_t*)d_ws;
    const size_t M1 = 1024 * 1024;
    // Region timeline (ushort units, 14M = 28 MB):
    //  0..2M   Xb     -> dead after QKV gemm -> Opart (0..4M)
    //  2..5M   Wt     -> dead after QKV gemm -> Lpart (at 4M)
    //  5..6M   Wot    (live until final gemm)
    //  6..12M  QKV    -> dead after attn     -> Ctx (6..8M)
    // 12..14M  Vt     (live until attn)
    ushort_t* Xb    = ws;
    ushort_t* Wt    = ws + 2 * M1;
    ushort_t* Wot   = ws + 5 * M1;
    ushort_t* QKV   = ws + 6 * M1;
    ushort_t* Vt    = ws + 12 * M1;
    ushort_t* Opart = ws;
    float*    Lpart = (float*)(ws + 4 * M1);
    ushort_t* Ctx   = ws + 6 * M1;

    prep<<<dim3(3072), 256, 0, stream>>>(X, Wq, Wk, Wv, Wo, Xb, Wt, Wot);
    gemm_bf16<<<dim3(24, 16), 256, 0, stream>>>(Xb, Wt, QKV, S_LEN, 3072, DMODEL);
    vt_trans<<<dim3(32, 16), 256, 0, stream>>>(QKV, Vt);
    attn_mfma<<<dim3(16, 16, 2), 256, 0, stream>>>(QKV, Vt, rb, Opart, Lpart);
    attn_reduce<<<dim3(S_LEN * DMODEL / 8 / 256), 256, 0, stream>>>(Opart, Lpart, Ctx);
    gemm64_f32<<<dim3(16, 32), 256, 0, stream>>>(Ctx, Wot, out, S_LEN, DMODEL, DMODEL);
}